// Round 1
// baseline (703.687 us; speedup 1.0000x reference)
//
#include <hip/hip_runtime.h>
#include <cmath>

#define Bn 4
#define Hn 32
#define Qn 64
#define Dn 128
#define Tn 4096
#define Rn 128
#define TILE 64
#define QB 32              // q rows per block
#define NTHREADS 512
#define SCALE_QK 0.08838834764831845f   // 1/sqrt(128)

// LDS row strides (floats), chosen to spread banks
#define QS_S 132
#define KT_S 132
#define VS_S 132
#define SS_S 68

__global__ __launch_bounds__(NTHREADS, 1)
void kivi_attn_kernel(const float* __restrict__ qry,
                      const int*   __restrict__ kcode,
                      const float* __restrict__ kscale,
                      const float* __restrict__ kmn,
                      const float* __restrict__ kfull,
                      const int*   __restrict__ vcode,
                      const float* __restrict__ vscale,
                      const float* __restrict__ vmn,
                      const float* __restrict__ vfull,
                      float* __restrict__ out)
{
    __shared__ float Qs[QB * QS_S];
    __shared__ float Kt[TILE * KT_S];
    __shared__ float Vs[TILE * VS_S];
    __shared__ float Ss[QB * SS_S];
    __shared__ float m_s[QB], l_s[QB], alpha_s[QB];

    const int tid  = threadIdx.x;
    const int bh   = blockIdx.x >> 1;     // 0..127  (b*H + h)
    const int qblk = blockIdx.x & 1;      // 0..1
    const int q0   = qblk * QB;           // first global q row of this block

    const float* qp  = qry    + (size_t)bh * Qn * Dn + (size_t)q0 * Dn;
    const int*   kc  = kcode  + (size_t)bh * Dn * (Tn / 8);
    const float* ks  = kscale + (size_t)bh * Dn * (Tn / 32);
    const float* km  = kmn    + (size_t)bh * Dn * (Tn / 32);
    const float* kf  = kfull  + (size_t)bh * Rn * Dn;
    const int*   vc  = vcode  + (size_t)bh * Tn * (Dn / 8);
    const float* vsc = vscale + (size_t)bh * Tn * (Dn / 32);
    const float* vm  = vmn    + (size_t)bh * Tn * (Dn / 32);
    const float* vf  = vfull  + (size_t)bh * Rn * Dn;

    // ---- load Q tile: QB*Dn = 4096 floats = 1024 float4 / 512 thr ----
    #pragma unroll
    for (int k = 0; k < 2; ++k) {
        int fidx = tid + k * NTHREADS;        // 0..1023
        int r    = fidx >> 5;                 // 0..31
        int c4   = (fidx & 31) << 2;          // 0..124
        *(float4*)&Qs[r * QS_S + c4] = *(const float4*)(qp + r * Dn + c4);
    }
    if (tid < QB) { m_s[tid] = -INFINITY; l_s[tid] = 0.f; }

    // ---- O accumulator: thread owns q = tid>>4, 8 d's at (tid&15)*8 ----
    float o[8];
    #pragma unroll
    for (int i = 0; i < 8; ++i) o[i] = 0.f;
    const int oq = tid >> 4;
    const int od = (tid & 15) << 3;

    // ---- score mapping: row sq, columns st + 16*i ----
    const int sq = tid >> 4;      // 0..31
    const int st = tid & 15;      // 0..15

    const int NT = Tn / TILE;     // 64 quantized tiles; +2 residual tiles
    for (int tile = 0; tile < NT + 2; ++tile) {
        __syncthreads();   // previous tile's consumers done before restage

        if (tile < NT) {
            // ---- dequantize K tile -> Kt[t_local][d] ----
            #pragma unroll
            for (int k = 0; k < 2; ++k) {
                int widx = tid + k * NTHREADS;      // 0..1023
                int d    = widx >> 3;               // 0..127
                int wj   = widx & 7;                // word within tile
                int tg   = tile * TILE + wj * 8;    // global t of nibble 0
                unsigned code = (unsigned)kc[d * (Tn / 8) + (tg >> 3)];
                float sc = ks[d * (Tn / 32) + (tg >> 5)];
                float mn = km[d * (Tn / 32) + (tg >> 5)];
                #pragma unroll
                for (int j = 0; j < 8; ++j) {
                    int val = (code >> (4 * j)) & 15;
                    Kt[(wj * 8 + j) * KT_S + d] = (float)val * sc + mn;
                }
            }
            // ---- dequantize V tile -> Vs[t_local][d] ----
            #pragma unroll
            for (int k = 0; k < 2; ++k) {
                int widx = tid + k * NTHREADS;      // 0..1023
                int tr   = widx >> 4;               // 0..63
                int wd   = widx & 15;               // word along d
                int tg   = tile * TILE + tr;
                unsigned code = (unsigned)vc[tg * (Dn / 8) + wd];
                float sc = vsc[tg * (Dn / 32) + (wd >> 2)];
                float mn = vm[tg * (Dn / 32) + (wd >> 2)];
                #pragma unroll
                for (int j = 0; j < 8; ++j) {
                    int val = (code >> (4 * j)) & 15;
                    Vs[tr * VS_S + wd * 8 + j] = (float)val * sc + mn;
                }
            }
        } else {
            // ---- residual fp32 tiles ----
            int rt = tile - NT;   // 0 or 1
            #pragma unroll
            for (int k = 0; k < 4; ++k) {
                int fidx = tid + k * NTHREADS;      // 0..2047
                int r    = fidx >> 5;               // 0..63
                int c4   = (fidx & 31) << 2;        // 0..124
                *(float4*)&Kt[r * KT_S + c4] =
                    *(const float4*)(kf + (size_t)(rt * TILE + r) * Dn + c4);
                *(float4*)&Vs[r * VS_S + c4] =
                    *(const float4*)(vf + (size_t)(rt * TILE + r) * Dn + c4);
            }
        }
        __syncthreads();

        // ---- S = Q K^T (per-thread 1q x 4t, float4 over d) ----
        float acc0 = 0.f, acc1 = 0.f, acc2 = 0.f, acc3 = 0.f;
        #pragma unroll 4
        for (int d0 = 0; d0 < Dn; d0 += 4) {
            float4 qv = *(const float4*)&Qs[sq * QS_S + d0];
            float4 k0 = *(const float4*)&Kt[(st     ) * KT_S + d0];
            float4 k1 = *(const float4*)&Kt[(st + 16) * KT_S + d0];
            float4 k2 = *(const float4*)&Kt[(st + 32) * KT_S + d0];
            float4 k3 = *(const float4*)&Kt[(st + 48) * KT_S + d0];
            acc0 = fmaf(qv.x, k0.x, fmaf(qv.y, k0.y, fmaf(qv.z, k0.z, fmaf(qv.w, k0.w, acc0))));
            acc1 = fmaf(qv.x, k1.x, fmaf(qv.y, k1.y, fmaf(qv.z, k1.z, fmaf(qv.w, k1.w, acc1))));
            acc2 = fmaf(qv.x, k2.x, fmaf(qv.y, k2.y, fmaf(qv.z, k2.z, fmaf(qv.w, k2.w, acc2))));
            acc3 = fmaf(qv.x, k3.x, fmaf(qv.y, k3.y, fmaf(qv.z, k3.z, fmaf(qv.w, k3.w, acc3))));
        }
        {
            float accs[4] = {acc0, acc1, acc2, acc3};
            const bool resid = (tile >= NT);
            const int rt = tile - NT;
            #pragma unroll
            for (int i = 0; i < 4; ++i) {
                int tl = st + 16 * i;
                float s = accs[i] * SCALE_QK;
                if (resid) {
                    int rg = rt * TILE + tl;
                    int qg = q0 + sq;
                    if (rg > (Rn - Qn) + qg) s = -1e30f;
                }
                Ss[sq * SS_S + tl] = s;
            }
        }
        __syncthreads();

        // ---- online softmax: wave wv handles rows wv*4 .. wv*4+3 ----
        {
            int wv = tid >> 6, lane = tid & 63;
            #pragma unroll
            for (int i = 0; i < 4; ++i) {
                int r = wv * 4 + i;
                float s = Ss[r * SS_S + lane];
                float mx = s;
                #pragma unroll
                for (int off = 32; off > 0; off >>= 1)
                    mx = fmaxf(mx, __shfl_xor(mx, off));
                float mold = m_s[r];
                float mnew = fmaxf(mold, mx);
                float p = __expf(s - mnew);
                float sum = p;
                #pragma unroll
                for (int off = 32; off > 0; off >>= 1)
                    sum += __shfl_xor(sum, off);
                Ss[r * SS_S + lane] = p;
                if (lane == 0) {
                    float alpha = __expf(mold - mnew);
                    l_s[r] = l_s[r] * alpha + sum;
                    m_s[r] = mnew;
                    alpha_s[r] = alpha;
                }
            }
        }
        __syncthreads();

        // ---- O rescale + P @ V ----
        {
            float alpha = alpha_s[oq];
            #pragma unroll
            for (int i = 0; i < 8; ++i) o[i] *= alpha;
            #pragma unroll 4
            for (int t = 0; t < TILE; ++t) {
                float p = Ss[oq * SS_S + t];
                float4 v0 = *(const float4*)&Vs[t * VS_S + od];
                float4 v1 = *(const float4*)&Vs[t * VS_S + od + 4];
                o[0] = fmaf(p, v0.x, o[0]);
                o[1] = fmaf(p, v0.y, o[1]);
                o[2] = fmaf(p, v0.z, o[2]);
                o[3] = fmaf(p, v0.w, o[3]);
                o[4] = fmaf(p, v1.x, o[4]);
                o[5] = fmaf(p, v1.y, o[5]);
                o[6] = fmaf(p, v1.z, o[6]);
                o[7] = fmaf(p, v1.w, o[7]);
            }
        }
    }

    // ---- epilogue: normalize and write ----
    float linv = 1.0f / l_s[oq];
    float* op = out + (size_t)bh * Qn * Dn + (size_t)(q0 + oq) * Dn + od;
    #pragma unroll
    for (int i = 0; i < 8; ++i) op[i] = o[i] * linv;
}

extern "C" void kernel_launch(void* const* d_in, const int* in_sizes, int n_in,
                              void* d_out, int out_size, void* d_ws, size_t ws_size,
                              hipStream_t stream) {
    const float* qry    = (const float*)d_in[0];
    const int*   kcode  = (const int*)  d_in[1];
    const float* kscale = (const float*)d_in[2];
    const float* kmn    = (const float*)d_in[3];
    const float* kfull  = (const float*)d_in[4];
    const int*   vcode  = (const int*)  d_in[5];
    const float* vscale = (const float*)d_in[6];
    const float* vmn    = (const float*)d_in[7];
    const float* vfull  = (const float*)d_in[8];
    float* out = (float*)d_out;

    dim3 grid(Bn * Hn * 2);
    dim3 block(NTHREADS);
    kivi_attn_kernel<<<grid, block, 0, stream>>>(
        qry, kcode, kscale, kmn, kfull, vcode, vscale, vmn, vfull, out);
}

// Round 2
// 217.396 us; speedup vs baseline: 3.2369x; 3.2369x over previous
//
#include <hip/hip_runtime.h>
#include <cmath>

#define Bn 4
#define Hn 32
#define Qn 64
#define Dn 128
#define Tn 4096
#define Rn 128
#define TILE 64
#define NT (Tn / TILE)        // 64 quantized tiles (+2 residual)
#define QB 32                 // q rows per block
#define NTHREADS 512
#define SCALE_QK 0.08838834764831845f

typedef __attribute__((ext_vector_type(8))) short short8;
typedef __attribute__((ext_vector_type(4))) float f32x4;

// LDS row strides in BYTES (each = multiple of 16, +16B pad to spread banks)
#define KP_RB 272      // Kp[t=64][d=128] bf16  (256 used + 16 pad)
#define VT_RB 144      // Vt[d=128][t=64] bf16  (128 used + 16 pad)
#define PL_RB 144      // Pl[q=32][t=64]  bf16
#define SS_S  68       // Ss stride in floats

__device__ __forceinline__ unsigned short f2bf(float f) {
    unsigned u = __builtin_bit_cast(unsigned, f);
    u = (u + 0x7FFFu + ((u >> 16) & 1u)) >> 16;   // RNE
    return (unsigned short)u;
}

__global__ __launch_bounds__(NTHREADS, 1)
void kivi_attn_mfma(const float* __restrict__ qry,
                    const int*   __restrict__ kcode,
                    const float* __restrict__ kscale,
                    const float* __restrict__ kmn,
                    const float* __restrict__ kfull,
                    const int*   __restrict__ vcode,
                    const float* __restrict__ vscale,
                    const float* __restrict__ vmn,
                    const float* __restrict__ vfull,
                    float* __restrict__ out)
{
    __shared__ __align__(16) char KpB[64 * KP_RB];    // 17408 B
    __shared__ __align__(16) char VtB[128 * VT_RB];   // 18432 B
    __shared__ __align__(16) float Ss[QB * SS_S];     //  8704 B
    __shared__ __align__(16) char PlB[QB * PL_RB];    //  4608 B
    __shared__ float m_s[QB], l_s[QB], alpha_s[QB];

    const int tid = threadIdx.x;
    const int bh  = blockIdx.x >> 1;
    const int q0  = (blockIdx.x & 1) * QB;

    const int*   kc  = kcode  + (size_t)bh * (Dn * (Tn / 8));
    const float* ksc = kscale + (size_t)bh * (Dn * (Tn / 32));
    const float* kmm = kmn    + (size_t)bh * (Dn * (Tn / 32));
    const float* kf  = kfull  + (size_t)bh * (Rn * Dn);
    const int*   vc  = vcode  + (size_t)bh * (Tn * (Dn / 8));
    const float* vsc = vscale + (size_t)bh * (Tn * (Dn / 32));
    const float* vmm = vmn    + (size_t)bh * (Tn * (Dn / 32));
    const float* vf  = vfull  + (size_t)bh * (Rn * Dn);

    const int wid = tid >> 6, lane = tid & 63;
    const int wr = wid >> 2, wc = wid & 3;       // wave tile-row (2) x tile-col (4)
    const int g = lane >> 4, r = lane & 15;      // MFMA lane coords

    // dequant thread mappings
    const int ktw = tid & 7,  kdp = tid >> 3;    // K: word-in-tile, d-pair
    const int vwd = tid & 15, vtp = tid >> 4;    // V: word-in-row, t-pair

    // ---- Q A-fragments, scale baked into bf16 ----
    short8 qa[4];
    {
        const float* qrow = qry + ((size_t)bh * Qn + (q0 + wr * 16 + r)) * Dn;
        #pragma unroll
        for (int m = 0; m < 4; ++m) {
            float4 f0 = *(const float4*)(qrow + m * 32 + 8 * g);
            float4 f1 = *(const float4*)(qrow + m * 32 + 8 * g + 4);
            short8 a;
            a[0] = (short)f2bf(f0.x * SCALE_QK); a[1] = (short)f2bf(f0.y * SCALE_QK);
            a[2] = (short)f2bf(f0.z * SCALE_QK); a[3] = (short)f2bf(f0.w * SCALE_QK);
            a[4] = (short)f2bf(f1.x * SCALE_QK); a[5] = (short)f2bf(f1.y * SCALE_QK);
            a[6] = (short)f2bf(f1.z * SCALE_QK); a[7] = (short)f2bf(f1.w * SCALE_QK);
            qa[m] = a;
        }
    }
    if (tid < QB) { m_s[tid] = -INFINITY; l_s[tid] = 0.f; }

    f32x4 acc0 = {0.f, 0.f, 0.f, 0.f};
    f32x4 acc1 = {0.f, 0.f, 0.f, 0.f};

    // ---- prefetch registers (codes + scales for next tile) ----
    int kc0, kc1, vc0, vc1;
    float ksc0, kmn0, ksc1, kmn1, vsc0, vmn0, vsc1, vmn1;
    auto prefetch = [&](int tile) {
        const int* kp = kc + (size_t)(kdp * 2) * (Tn / 8) + tile * 8 + ktw;
        kc0 = kp[0]; kc1 = kp[Tn / 8];
        int tcol = tile * 2 + (ktw >> 2);
        ksc0 = ksc[(kdp * 2    ) * (Tn / 32) + tcol];
        kmn0 = kmm[(kdp * 2    ) * (Tn / 32) + tcol];
        ksc1 = ksc[(kdp * 2 + 1) * (Tn / 32) + tcol];
        kmn1 = kmm[(kdp * 2 + 1) * (Tn / 32) + tcol];
        int tg = tile * TILE + 2 * vtp;
        vc0 = vc[(size_t)tg * (Dn / 8) + vwd];
        vc1 = vc[(size_t)(tg + 1) * (Dn / 8) + vwd];
        vsc0 = vsc[tg * (Dn / 32) + (vwd >> 2)];
        vmn0 = vmm[tg * (Dn / 32) + (vwd >> 2)];
        vsc1 = vsc[(tg + 1) * (Dn / 32) + (vwd >> 2)];
        vmn1 = vmm[(tg + 1) * (Dn / 32) + (vwd >> 2)];
    };
    prefetch(0);

    for (int tile = 0; tile < NT + 2; ++tile) {
        __syncthreads();   // previous tile's LDS consumers done

        if (tile < NT) {
            // ---- K dequant: pairs (d0, d0+1) for t = 8*ktw + j ----
            {
                unsigned xv = (unsigned)(ktw << 4);   // ((t>>3)&7)<<4, t>>3 == ktw
                unsigned c0 = (unsigned)kc0, c1 = (unsigned)kc1;
                #pragma unroll
                for (int j = 0; j < 8; ++j) {
                    int t = 8 * ktw + j;
                    float v0 = (float)((c0 >> (4 * j)) & 15u) * ksc0 + kmn0;
                    float v1 = (float)((c1 >> (4 * j)) & 15u) * ksc1 + kmn1;
                    unsigned pk = (unsigned)f2bf(v0) | ((unsigned)f2bf(v1) << 16);
                    *(unsigned*)(KpB + ((t * KP_RB + 4 * kdp) ^ xv)) = pk;
                }
            }
            // ---- V dequant: pairs (t0, t0+1) for d = 8*vwd + j ----
            {
                unsigned xv = (unsigned)((vwd & 7) << 4);  // ((d>>3)&7)<<4, d>>3 == vwd
                unsigned c0 = (unsigned)vc0, c1 = (unsigned)vc1;
                #pragma unroll
                for (int j = 0; j < 8; ++j) {
                    int d = 8 * vwd + j;
                    float v0 = (float)((c0 >> (4 * j)) & 15u) * vsc0 + vmn0;
                    float v1 = (float)((c1 >> (4 * j)) & 15u) * vsc1 + vmn1;
                    unsigned pk = (unsigned)f2bf(v0) | ((unsigned)f2bf(v1) << 16);
                    *(unsigned*)(VtB + ((d * VT_RB + 4 * vtp) ^ xv)) = pk;
                }
            }
            if (tile + 1 < NT) prefetch(tile + 1);   // hide next tile's loads under compute
        } else {
            int rt = tile - NT;
            // ---- K residual fp32 tile: thread (t = tid&63, dg = tid>>6) ----
            {
                int t = tid & 63, dg = tid >> 6;
                const float* kr = kf + (size_t)(rt * TILE + t) * Dn + dg * 16;
                unsigned xv = (unsigned)(((t >> 3) & 7) << 4);
                #pragma unroll
                for (int s = 0; s < 2; ++s) {
                    float4 f0 = *(const float4*)(kr + s * 8);
                    float4 f1 = *(const float4*)(kr + s * 8 + 4);
                    short8 a;
                    a[0] = (short)f2bf(f0.x); a[1] = (short)f2bf(f0.y);
                    a[2] = (short)f2bf(f0.z); a[3] = (short)f2bf(f0.w);
                    a[4] = (short)f2bf(f1.x); a[5] = (short)f2bf(f1.y);
                    a[6] = (short)f2bf(f1.z); a[7] = (short)f2bf(f1.w);
                    *(short8*)(KpB + ((t * KP_RB + dg * 32 + s * 16) ^ xv)) = a;
                }
            }
            // ---- V residual fp32 tile: thread (d = tid&127, th = tid>>7) ----
            {
                int d = tid & 127, th = tid >> 7;
                const float* vr = vf + (size_t)(rt * TILE + th * 16) * Dn + d;
                unsigned xv = (unsigned)(((d >> 3) & 7) << 4);
                #pragma unroll
                for (int s = 0; s < 2; ++s) {
                    short8 a;
                    #pragma unroll
                    for (int i = 0; i < 8; ++i)
                        a[i] = (short)f2bf(vr[(size_t)(s * 8 + i) * Dn]);
                    *(short8*)(VtB + ((d * VT_RB + th * 32 + s * 16) ^ xv)) = a;
                }
            }
        }
        __syncthreads();

        // ---- S = Q K^T via MFMA: wave (wr,wc) computes 16x16 tile ----
        {
            f32x4 s = {0.f, 0.f, 0.f, 0.f};
            unsigned kxv = (unsigned)(((2 * wc + (r >> 3)) & 7) << 4);
            int krow = (wc * 16 + r) * KP_RB;
            #pragma unroll
            for (int m = 0; m < 4; ++m) {
                short8 b = *(const short8*)(KpB + ((krow + 64 * m + 16 * g) ^ kxv));
                s = __builtin_amdgcn_mfma_f32_16x16x32_bf16(qa[m], b, s, 0, 0, 0);
            }
            #pragma unroll
            for (int reg = 0; reg < 4; ++reg)
                Ss[(wr * 16 + 4 * g + reg) * SS_S + wc * 16 + r] = s[reg];
        }
        __syncthreads();

        // ---- online softmax: wave wid owns rows 4*wid..4*wid+3 ----
        #pragma unroll
        for (int i = 0; i < 4; ++i) {
            int rl = 4 * wid + i;
            float s = Ss[rl * SS_S + lane];
            if (tile >= NT) {
                int rg = (tile - NT) * TILE + lane;
                if (rg > (Rn - Qn) + q0 + rl) s = -1e30f;
            }
            float mx = s;
            #pragma unroll
            for (int off = 32; off > 0; off >>= 1)
                mx = fmaxf(mx, __shfl_xor(mx, off));
            float mold = m_s[rl];
            float mnew = fmaxf(mold, mx);
            float p = __expf(s - mnew);
            float sum = p;
            #pragma unroll
            for (int off = 32; off > 0; off >>= 1)
                sum += __shfl_xor(sum, off);
            *(unsigned short*)(PlB + rl * PL_RB + 2 * lane) = f2bf(p);
            if (lane == 0) {
                float alpha = __expf(mold - mnew);
                l_s[rl] = l_s[rl] * alpha + sum;
                m_s[rl] = mnew;
                alpha_s[rl] = alpha;
            }
        }
        __syncthreads();

        // ---- O = O*alpha + P V via MFMA: wave (wr,wc) -> rows wr*16, d cols wc*32..+31 ----
        {
            float ar[4];
            #pragma unroll
            for (int reg = 0; reg < 4; ++reg) ar[reg] = alpha_s[wr * 16 + 4 * g + reg];
            #pragma unroll
            for (int reg = 0; reg < 4; ++reg) { acc0[reg] *= ar[reg]; acc1[reg] *= ar[reg]; }
            int prow = (wr * 16 + r) * PL_RB;
            int rowA = wc * 32 + r, rowB = wc * 32 + 16 + r;   // Vt rows (d index)
            unsigned xva = (unsigned)(((rowA >> 3) & 7) << 4);
            unsigned xvb = (unsigned)(((rowB >> 3) & 7) << 4);
            #pragma unroll
            for (int ks2 = 0; ks2 < 2; ++ks2) {
                short8 pa = *(const short8*)(PlB + prow + 64 * ks2 + 16 * g);
                short8 v0 = *(const short8*)(VtB + ((rowA * VT_RB + 64 * ks2 + 16 * g) ^ xva));
                short8 v1 = *(const short8*)(VtB + ((rowB * VT_RB + 64 * ks2 + 16 * g) ^ xvb));
                acc0 = __builtin_amdgcn_mfma_f32_16x16x32_bf16(pa, v0, acc0, 0, 0, 0);
                acc1 = __builtin_amdgcn_mfma_f32_16x16x32_bf16(pa, v1, acc1, 0, 0, 0);
            }
        }
    }

    __syncthreads();
    // ---- epilogue: normalize + store ----
    {
        float* orow = out + ((size_t)bh * Qn + q0 + wr * 16) * Dn;
        #pragma unroll
        for (int reg = 0; reg < 4; ++reg) {
            float linv = 1.0f / l_s[wr * 16 + 4 * g + reg];
            orow[(size_t)(4 * g + reg) * Dn + wc * 32 + r]      = acc0[reg] * linv;
            orow[(size_t)(4 * g + reg) * Dn + wc * 32 + 16 + r] = acc1[reg] * linv;
        }
    }
}

extern "C" void kernel_launch(void* const* d_in, const int* in_sizes, int n_in,
                              void* d_out, int out_size, void* d_ws, size_t ws_size,
                              hipStream_t stream) {
    const float* qry    = (const float*)d_in[0];
    const int*   kcode  = (const int*)  d_in[1];
    const float* kscale = (const float*)d_in[2];
    const float* kmn    = (const float*)d_in[3];
    const float* kfull  = (const float*)d_in[4];
    const int*   vcode  = (const int*)  d_in[5];
    const float* vscale = (const float*)d_in[6];
    const float* vmn    = (const float*)d_in[7];
    const float* vfull  = (const float*)d_in[8];
    float* out = (float*)d_out;

    dim3 grid(Bn * Hn * 2);
    dim3 block(NTHREADS);
    kivi_attn_mfma<<<grid, block, 0, stream>>>(
        qry, kcode, kscale, kmn, kfull, vcode, vscale, vmn, vfull, out);
}

// Round 4
// 167.094 us; speedup vs baseline: 4.2113x; 1.3010x over previous
//
#include <hip/hip_runtime.h>
#include <hip/hip_bf16.h>
#include <cmath>

#define Bn 4
#define Hn 32
#define Qn 64
#define Dn 128
#define Tn 4096
#define Rn 128
#define TILE 64
#define NT (Tn / TILE)        // 64 quantized tiles (+2 residual)
#define QB 32                 // q rows per block
#define NTHREADS 512
#define SCALE_QK 0.08838834764831845f
#define SPLIT_MID 33          // chunk0: tiles [0,33), chunk1: [33,66)

typedef __attribute__((ext_vector_type(8))) short short8;
typedef __attribute__((ext_vector_type(4))) float f32x4;
typedef __attribute__((ext_vector_type(4))) unsigned uintx4;

// LDS row strides in BYTES
#define KP_RB 272      // Kp[t=64][d=128] bf16 (+16B pad)
#define VT_RB 144      // Vt[d=128][t=64] bf16 (+16B pad)
#define PL_RB 144      // Pl[q=32][t=64]  bf16
#define SS_S  68       // Ss stride in floats

__device__ __forceinline__ unsigned pk2(float a, float b) {
    __hip_bfloat162 h = __float22bfloat162_rn(make_float2(a, b));
    unsigned u;
    __builtin_memcpy(&u, &h, 4);
    return u;
}
__device__ __forceinline__ short8 pack8(float4 f0, float4 f1) {
    uintx4 u = { pk2(f0.x, f0.y), pk2(f0.z, f0.w), pk2(f1.x, f1.y), pk2(f1.z, f1.w) };
    short8 s;
    __builtin_memcpy(&s, &u, 16);
    return s;
}

template<bool SPLIT>
__global__ __launch_bounds__(NTHREADS, 4)
void kivi_attn_mfma(const float* __restrict__ qry,
                    const int*   __restrict__ kcode,
                    const float* __restrict__ kscale,
                    const float* __restrict__ kmn,
                    const float* __restrict__ kfull,
                    const int*   __restrict__ vcode,
                    const float* __restrict__ vscale,
                    const float* __restrict__ vmn,
                    const float* __restrict__ vfull,
                    float* __restrict__ out,
                    float* __restrict__ wsO)
{
    __shared__ __align__(16) char KpB[64 * KP_RB];
    __shared__ __align__(16) char VtB[128 * VT_RB];
    __shared__ __align__(16) float Ss[QB * SS_S];
    __shared__ __align__(16) char PlB[QB * PL_RB];
    __shared__ float m_s[QB], l_s[QB], alpha_s[QB];

    const int tid = threadIdx.x;
    int bh, q0, lo, hi;
    if (SPLIT) {
        bh = blockIdx.x >> 2;
        q0 = ((blockIdx.x >> 1) & 1) * QB;
        lo = (blockIdx.x & 1) ? SPLIT_MID : 0;
        hi = (blockIdx.x & 1) ? (NT + 2) : SPLIT_MID;
    } else {
        bh = blockIdx.x >> 1;
        q0 = (blockIdx.x & 1) * QB;
        lo = 0; hi = NT + 2;
    }
    const int pf_hi = hi < NT ? hi : NT;

    const int*   kc  = kcode  + (size_t)bh * (Dn * (Tn / 8));
    const float* ksc = kscale + (size_t)bh * (Dn * (Tn / 32));
    const float* kmm = kmn    + (size_t)bh * (Dn * (Tn / 32));
    const float* kf  = kfull  + (size_t)bh * (Rn * Dn);
    const int*   vc  = vcode  + (size_t)bh * (Tn * (Dn / 8));
    const float* vsc = vscale + (size_t)bh * (Tn * (Dn / 32));
    const float* vmm = vmn    + (size_t)bh * (Tn * (Dn / 32));
    const float* vf  = vfull  + (size_t)bh * (Rn * Dn);

    const int wid = tid >> 6, lane = tid & 63;
    const int wr = wid >> 2, wc = wid & 3;
    const int g = lane >> 4, r = lane & 15;

    const int ktw = tid & 7,  kdp = tid >> 3;    // K: word-in-tile, d-pair
    const int vwd = tid & 15, vtp = tid >> 4;    // V: word-in-row, t-pair

    // ---- Q A-fragments (scale baked in) ----
    short8 qa[4];
    {
        const float* qrow = qry + ((size_t)bh * Qn + (q0 + wr * 16 + r)) * Dn;
        #pragma unroll
        for (int m = 0; m < 4; ++m) {
            float4 f0 = *(const float4*)(qrow + m * 32 + 8 * g);
            float4 f1 = *(const float4*)(qrow + m * 32 + 8 * g + 4);
            f0.x *= SCALE_QK; f0.y *= SCALE_QK; f0.z *= SCALE_QK; f0.w *= SCALE_QK;
            f1.x *= SCALE_QK; f1.y *= SCALE_QK; f1.z *= SCALE_QK; f1.w *= SCALE_QK;
            qa[m] = pack8(f0, f1);
        }
    }
    if (tid < QB) { m_s[tid] = -INFINITY; l_s[tid] = 0.f; }

    f32x4 acc0 = {0.f, 0.f, 0.f, 0.f};
    f32x4 acc1 = {0.f, 0.f, 0.f, 0.f};

    // ---- running prefetch pointers (codes + scales) ----
    const int*   kpp  = kc  + (size_t)(kdp * 2) * (Tn / 8) + lo * 8 + ktw;          // +8/tile
    const float* kscp = ksc + (size_t)(kdp * 2) * (Tn / 32) + lo * 2 + (ktw >> 2);  // +2/tile
    const float* kmmp = kmm + (size_t)(kdp * 2) * (Tn / 32) + lo * 2 + (ktw >> 2);
    const int*   vcp  = vc  + ((size_t)lo * TILE + 2 * vtp) * (Dn / 8) + vwd;        // +1024/tile
    const float* vscp = vsc + ((size_t)lo * TILE + 2 * vtp) * (Dn / 32) + (vwd >> 2); // +256/tile
    const float* vmmp = vmm + ((size_t)lo * TILE + 2 * vtp) * (Dn / 32) + (vwd >> 2);

    int kc0, kc1, vc0, vc1;
    float ksc0, kmn0, ksc1, kmn1, vsc0, vmn0, vsc1, vmn1;
    auto pf = [&]() {
        kc0 = kpp[0]; kc1 = kpp[Tn / 8];
        ksc0 = kscp[0]; ksc1 = kscp[Tn / 32];
        kmn0 = kmmp[0]; kmn1 = kmmp[Tn / 32];
        vc0 = vcp[0]; vc1 = vcp[Dn / 8];
        vsc0 = vscp[0]; vsc1 = vscp[Dn / 32];
        vmn0 = vmmp[0]; vmn1 = vmmp[Dn / 32];
        kpp += 8; kscp += 2; kmmp += 2;
        vcp += TILE * (Dn / 8); vscp += TILE * (Dn / 32); vmmp += TILE * (Dn / 32);
    };
    pf();   // tile `lo`

    for (int tile = lo; tile < hi; ++tile) {
        __syncthreads();   // B1: previous tile's LDS consumers done

        if (tile < NT) {
            {   // K dequant: pairs (d0,d0+1) for t = 8*ktw + j
                unsigned xv = (unsigned)(ktw << 4);
                unsigned c0 = (unsigned)kc0, c1 = (unsigned)kc1;
                #pragma unroll
                for (int j = 0; j < 8; ++j) {
                    int t = 8 * ktw + j;
                    float v0 = (float)((c0 >> (4 * j)) & 15u) * ksc0 + kmn0;
                    float v1 = (float)((c1 >> (4 * j)) & 15u) * ksc1 + kmn1;
                    *(unsigned*)(KpB + ((t * KP_RB + 4 * kdp) ^ xv)) = pk2(v0, v1);
                }
            }
            {   // V dequant: pairs (t0,t0+1) for d = 8*vwd + j
                unsigned xv = (unsigned)((vwd & 7) << 4);
                unsigned c0 = (unsigned)vc0, c1 = (unsigned)vc1;
                #pragma unroll
                for (int j = 0; j < 8; ++j) {
                    int d = 8 * vwd + j;
                    float v0 = (float)((c0 >> (4 * j)) & 15u) * vsc0 + vmn0;
                    float v1 = (float)((c1 >> (4 * j)) & 15u) * vsc1 + vmn1;
                    *(unsigned*)(VtB + ((d * VT_RB + 4 * vtp) ^ xv)) = pk2(v0, v1);
                }
            }
        } else {
            int rt = tile - NT;
            {   // K residual fp32 tile
                int t = tid & 63, dg = tid >> 6;
                const float* kr = kf + (size_t)(rt * TILE + t) * Dn + dg * 16;
                unsigned xv = (unsigned)(((t >> 3) & 7) << 4);
                #pragma unroll
                for (int s = 0; s < 2; ++s) {
                    float4 f0 = *(const float4*)(kr + s * 8);
                    float4 f1 = *(const float4*)(kr + s * 8 + 4);
                    *(short8*)(KpB + ((t * KP_RB + dg * 32 + s * 16) ^ xv)) = pack8(f0, f1);
                }
            }
            {   // V residual fp32 tile
                int d = tid & 127, th = tid >> 7;
                const float* vr = vf + (size_t)(rt * TILE + th * 16) * Dn + d;
                unsigned xv = (unsigned)(((d >> 3) & 7) << 4);
                #pragma unroll
                for (int s = 0; s < 2; ++s) {
                    float4 f0, f1;
                    f0.x = vr[(size_t)(s * 8 + 0) * Dn]; f0.y = vr[(size_t)(s * 8 + 1) * Dn];
                    f0.z = vr[(size_t)(s * 8 + 2) * Dn]; f0.w = vr[(size_t)(s * 8 + 3) * Dn];
                    f1.x = vr[(size_t)(s * 8 + 4) * Dn]; f1.y = vr[(size_t)(s * 8 + 5) * Dn];
                    f1.z = vr[(size_t)(s * 8 + 6) * Dn]; f1.w = vr[(size_t)(s * 8 + 7) * Dn];
                    *(short8*)(VtB + ((d * VT_RB + th * 32 + s * 16) ^ xv)) = pack8(f0, f1);
                }
            }
        }
        __syncthreads();   // B2

        // ---- S = Q K^T via MFMA ----
        {
            f32x4 s = {0.f, 0.f, 0.f, 0.f};
            unsigned kxv = (unsigned)(((2 * wc + (r >> 3)) & 7) << 4);
            int krow = (wc * 16 + r) * KP_RB;
            #pragma unroll
            for (int m = 0; m < 4; ++m) {
                short8 b = *(const short8*)(KpB + ((krow + 64 * m + 16 * g) ^ kxv));
                s = __builtin_amdgcn_mfma_f32_16x16x32_bf16(qa[m], b, s, 0, 0, 0);
            }
            #pragma unroll
            for (int reg = 0; reg < 4; ++reg)
                Ss[(wr * 16 + 4 * g + reg) * SS_S + wc * 16 + r] = s[reg];
        }
        __syncthreads();   // B3

        // ---- issue next tile's global loads; drained at B4, covered by softmax ----
        if (tile + 1 < pf_hi) pf();

        // ---- online softmax: wave wid owns rows 4*wid..4*wid+3 ----
        #pragma unroll
        for (int i = 0; i < 4; ++i) {
            int rl = 4 * wid + i;
            float s = Ss[rl * SS_S + lane];
            if (tile >= NT) {
                int rg = (tile - NT) * TILE + lane;
                if (rg > (Rn - Qn) + q0 + rl) s = -1e30f;
            }
            float mx = s;
            #pragma unroll
            for (int off = 32; off > 0; off >>= 1)
                mx = fmaxf(mx, __shfl_xor(mx, off));
            float mold = m_s[rl];
            float mnew = fmaxf(mold, mx);
            float p = __expf(s - mnew);
            float sum = p;
            #pragma unroll
            for (int off = 32; off > 0; off >>= 1)
                sum += __shfl_xor(sum, off);
            *(unsigned short*)(PlB + rl * PL_RB + 2 * lane) = (unsigned short)(pk2(p, 0.f) & 0xFFFFu);
            if (lane == 0) {
                float alpha = __expf(mold - mnew);
                l_s[rl] = l_s[rl] * alpha + sum;
                m_s[rl] = mnew;
                alpha_s[rl] = alpha;
            }
        }
        __syncthreads();   // B4

        // ---- O = O*alpha + P V via MFMA ----
        {
            float ar[4];
            #pragma unroll
            for (int reg = 0; reg < 4; ++reg) ar[reg] = alpha_s[wr * 16 + 4 * g + reg];
            #pragma unroll
            for (int reg = 0; reg < 4; ++reg) { acc0[reg] *= ar[reg]; acc1[reg] *= ar[reg]; }
            int prow = (wr * 16 + r) * PL_RB;
            int rowA = wc * 32 + r, rowB = wc * 32 + 16 + r;
            unsigned xva = (unsigned)(((rowA >> 3) & 7) << 4);
            unsigned xvb = (unsigned)(((rowB >> 3) & 7) << 4);
            #pragma unroll
            for (int ks2 = 0; ks2 < 2; ++ks2) {
                short8 pa = *(const short8*)(PlB + prow + 64 * ks2 + 16 * g);
                short8 v0 = *(const short8*)(VtB + ((rowA * VT_RB + 64 * ks2 + 16 * g) ^ xva));
                short8 v1 = *(const short8*)(VtB + ((rowB * VT_RB + 64 * ks2 + 16 * g) ^ xvb));
                acc0 = __builtin_amdgcn_mfma_f32_16x16x32_bf16(pa, v0, acc0, 0, 0, 0);
                acc1 = __builtin_amdgcn_mfma_f32_16x16x32_bf16(pa, v1, acc1, 0, 0, 0);
            }
        }
    }

    __syncthreads();
    if (SPLIT) {
        float* Op = wsO + (size_t)blockIdx.x * QB * Dn;
        #pragma unroll
        for (int reg = 0; reg < 4; ++reg) {
            int row = wr * 16 + 4 * g + reg;
            Op[(size_t)row * Dn + wc * 32 + r]      = acc0[reg];
            Op[(size_t)row * Dn + wc * 32 + 16 + r] = acc1[reg];
        }
        float* mp = wsO + (size_t)512 * QB * Dn;
        float* lp = mp + 512 * QB;
        if (tid < QB) {
            mp[blockIdx.x * QB + tid] = m_s[tid];
            lp[blockIdx.x * QB + tid] = l_s[tid];
        }
    } else {
        float* orow = out + ((size_t)bh * Qn + q0 + wr * 16) * Dn;
        #pragma unroll
        for (int reg = 0; reg < 4; ++reg) {
            float linv = 1.0f / l_s[wr * 16 + 4 * g + reg];
            orow[(size_t)(4 * g + reg) * Dn + wc * 32 + r]      = acc0[reg] * linv;
            orow[(size_t)(4 * g + reg) * Dn + wc * 32 + 16 + r] = acc1[reg] * linv;
        }
    }
}

__global__ __launch_bounds__(512, 1)
void kivi_combine(const float* __restrict__ ws, float* __restrict__ out)
{
    const int cb = blockIdx.x;          // 0..255 = bh*2 + qblk
    const int tid = threadIdx.x;
    const int row = tid >> 4, d0 = (tid & 15) << 3;
    const float* mp = ws + (size_t)512 * QB * Dn;
    const float* lp = mp + 512 * QB;
    const int p0 = cb * 2, p1 = p0 + 1;
    float m0 = mp[p0 * QB + row], m1 = mp[p1 * QB + row];
    float M = fmaxf(m0, m1);
    float w0 = __expf(m0 - M), w1 = __expf(m1 - M);
    float linv = 1.f / (lp[p0 * QB + row] * w0 + lp[p1 * QB + row] * w1);
    const float* O0 = ws + ((size_t)p0 * QB + row) * Dn + d0;
    const float* O1 = ws + ((size_t)p1 * QB + row) * Dn + d0;
    float* o = out + ((size_t)cb * QB + row) * Dn + d0;
    #pragma unroll
    for (int i = 0; i < 8; ++i)
        o[i] = (O0[i] * w0 + O1[i] * w1) * linv;
}

extern "C" void kernel_launch(void* const* d_in, const int* in_sizes, int n_in,
                              void* d_out, int out_size, void* d_ws, size_t ws_size,
                              hipStream_t stream) {
    const float* qry    = (const float*)d_in[0];
    const int*   kcode  = (const int*)  d_in[1];
    const float* kscale = (const float*)d_in[2];
    const float* kmn    = (const float*)d_in[3];
    const float* kfull  = (const float*)d_in[4];
    const int*   vcode  = (const int*)  d_in[5];
    const float* vscale = (const float*)d_in[6];
    const float* vmn    = (const float*)d_in[7];
    const float* vfull  = (const float*)d_in[8];
    float* out = (float*)d_out;
    float* ws  = (float*)d_ws;

    const size_t need = ((size_t)512 * QB * Dn + 2 * 512 * QB) * sizeof(float);
    if (ws_size >= need) {
        kivi_attn_mfma<true><<<dim3(Bn * Hn * 2 * 2), dim3(NTHREADS), 0, stream>>>(
            qry, kcode, kscale, kmn, kfull, vcode, vscale, vmn, vfull, out, ws);
        kivi_combine<<<dim3(Bn * Hn * 2), dim3(512), 0, stream>>>(ws, out);
    } else {
        kivi_attn_mfma<false><<<dim3(Bn * Hn * 2), dim3(NTHREADS), 0, stream>>>(
            qry, kcode, kscale, kmn, kfull, vcode, vscale, vmn, vfull, out, ws);
    }
}

// Round 5
// 138.896 us; speedup vs baseline: 5.0663x; 1.2030x over previous
//
#include <hip/hip_runtime.h>
#include <hip/hip_bf16.h>
#include <cmath>

#define Bn 4
#define Hn 32
#define Qn 64
#define Dn 128
#define Tn 4096
#define Rn 128
#define NTHREADS 512
#define SCALE_QK 0.08838834764831845f
#define NUNITS 66      // 64 quantized KV tiles of 64 + 2 residual tiles

typedef __attribute__((ext_vector_type(8))) short short8;
typedef __attribute__((ext_vector_type(4))) float f32x4;

__device__ __forceinline__ unsigned pk2(float a, float b) {
    __hip_bfloat162 h = __float22bfloat162_rn(make_float2(a, b));
    unsigned u; __builtin_memcpy(&u, &h, 4); return u;
}
__device__ __forceinline__ short8 pack8(float4 f0, float4 f1) {
    unsigned u[4] = { pk2(f0.x,f0.y), pk2(f0.z,f0.w), pk2(f1.x,f1.y), pk2(f1.z,f1.w) };
    short8 s; __builtin_memcpy(&s, u, 16); return s;
}
__device__ __forceinline__ unsigned dq2(unsigned c0, unsigned c1, int j,
                                        float s0, float m0, float s1, float m1) {
    float v0 = (float)((c0 >> (4*j)) & 15u) * s0 + m0;
    float v1 = (float)((c1 >> (4*j)) & 15u) * s1 + m1;
    return pk2(v0, v1);
}

// LDS map (single 40KB arena):
//   KpB = SMEM          : K tile  [t=64][d=128] bf16, 256B rows, XOR key ((t&7)^((t>>3)&7))<<4
//   VtB = SMEM + 16384  : V^T     [d=128][t=64] bf16, 128B rows, XOR key ((d&7)^((d>>3)&7))<<4
//   PlB = SMEM + 32768  : P       [q=64][t=64]  bf16, 128B rows, XOR key ((q&7)^((q>>3)&7))<<4
//   final merge overlays SMEM[0..32768) as O-scratch [64][128] f32
template<int NS>
__global__ __launch_bounds__(NTHREADS, 4)
void kivi_attn(const float* __restrict__ qry,
               const int*   __restrict__ kcode,
               const float* __restrict__ kscale,
               const float* __restrict__ kmn,
               const float* __restrict__ kfull,
               const int*   __restrict__ vcode,
               const float* __restrict__ vscale,
               const float* __restrict__ vmn,
               const float* __restrict__ vfull,
               float* __restrict__ out,
               float* __restrict__ ws)
{
    __shared__ __align__(16) char SMEM[40960];
    __shared__ float mlA[2][64];   // th0 half: [m/l][q]
    __shared__ float mlB[2][64];   // th1 half
    __shared__ float al_s[8][16];  // per-wave alpha
    char* KpB = SMEM;
    char* VtB = SMEM + 16384;
    char* PlB = SMEM + 32768;

    const int tid = threadIdx.x;
    const int bh  = blockIdx.x / NS;
    const int sp  = blockIdx.x % NS;
    const int pb  = bh * NS + sp;
    const int ulo = (sp * NUNITS) / NS;
    const int uhi = ((sp + 1) * NUNITS) / NS;

    const int*   kc  = kcode  + (size_t)bh * (Dn * (Tn / 8));
    const float* ksc = kscale + (size_t)bh * (Dn * (Tn / 32));
    const float* kmm = kmn    + (size_t)bh * (Dn * (Tn / 32));
    const float* kf  = kfull  + (size_t)bh * (Rn * Dn);
    const int*   vc  = vcode  + (size_t)bh * (Tn * (Dn / 8));
    const float* vsc = vscale + (size_t)bh * (Tn * (Dn / 32));
    const float* vmm = vmn    + (size_t)bh * (Tn * (Dn / 32));
    const float* vf  = vfull  + (size_t)bh * (Rn * Dn);

    const int w    = tid >> 6;        // wave 0..7
    const int lane = tid & 63;
    const int qg   = w & 3;           // q-group (16 rows each)
    const int th   = w >> 2;          // t-half 0/1
    const int g    = lane >> 4;       // MFMA group
    const int r    = lane & 15;       // MFMA row/col lane

    // dequant-stage thread mappings
    const int ktw = tid & 7,  kdp = tid >> 3;    // K: t-octet, d-pair (0..63)
    const int vwd = tid & 15, vtp = tid >> 4;    // V: d-octet-word, t-pair (0..31)

    // ---- Q B-fragments (scale baked in): lane holds Q[q=16qg+r][k=32m+8g..+7] ----
    short8 qb[4];
    {
        const float* qrow = qry + ((size_t)bh * Qn + (16 * qg + r)) * Dn;
        #pragma unroll
        for (int m = 0; m < 4; ++m) {
            float4 f0 = *(const float4*)(qrow + m * 32 + 8 * g);
            float4 f1 = *(const float4*)(qrow + m * 32 + 8 * g + 4);
            f0.x *= SCALE_QK; f0.y *= SCALE_QK; f0.z *= SCALE_QK; f0.w *= SCALE_QK;
            f1.x *= SCALE_QK; f1.y *= SCALE_QK; f1.z *= SCALE_QK; f1.w *= SCALE_QK;
            qb[m] = pack8(f0, f1);
        }
    }

    f32x4 o[8];
    #pragma unroll
    for (int nd = 0; nd < 8; ++nd) o[nd] = (f32x4){0.f, 0.f, 0.f, 0.f};
    float m_run = -INFINITY, l_run = 0.f;

    // ---- running prefetch pointers ----
    const int*   kpp  = kc  + (size_t)(2 * kdp) * (Tn / 8)  + ulo * 8 + ktw;
    const float* kscp = ksc + (size_t)(2 * kdp) * (Tn / 32) + ulo * 2 + (ktw >> 2);
    const float* kmmp = kmm + (size_t)(2 * kdp) * (Tn / 32) + ulo * 2 + (ktw >> 2);
    const int*   vcp  = vc  + ((size_t)ulo * 64 + 2 * vtp) * (Dn / 8)  + vwd;
    const float* vscp = vsc + ((size_t)ulo * 64 + 2 * vtp) * (Dn / 32) + (vwd >> 2);
    const float* vmmp = vmm + ((size_t)ulo * 64 + 2 * vtp) * (Dn / 32) + (vwd >> 2);

    int kc0, kc1, vc0, vc1;
    float ksc0, kmn0, ksc1, kmn1, vsc0, vmn0, vsc1, vmn1;
    auto pf = [&]() {
        kc0 = kpp[0]; kc1 = kpp[Tn / 8];
        ksc0 = kscp[0]; ksc1 = kscp[Tn / 32];
        kmn0 = kmmp[0]; kmn1 = kmmp[Tn / 32];
        vc0 = vcp[0]; vc1 = vcp[Dn / 8];
        vsc0 = vscp[0]; vsc1 = vscp[Dn / 32];
        vmn0 = vmmp[0]; vmn1 = vmmp[Dn / 32];
        kpp += 8; kscp += 2; kmmp += 2;
        vcp += 64 * (Dn / 8); vscp += 64 * (Dn / 32); vmmp += 64 * (Dn / 32);
    };
    pf();   // unit ulo (always quantized for NS<=4)

    const int q    = 16 * qg + r;                               // this lane's softmax q-row
    const int pkey = (((q & 7) ^ ((q >> 3) & 7)) << 4);

    for (int u = ulo; u < uhi; ++u) {
        __syncthreads();   // B1: all consumers of previous tile done

        if (u < 64) {
            {   // K dequant: word-pair rows (d=2kdp, 2kdp+1), t = 8*ktw + j
                unsigned c0 = (unsigned)kc0, c1 = (unsigned)kc1;
                #pragma unroll
                for (int j = 0; j < 8; ++j) {
                    int t = 8 * ktw + j;
                    int key = (j ^ ktw) << 4;
                    *(unsigned*)(KpB + (((t << 8) + 4 * kdp) ^ key)) =
                        dq2(c0, c1, j, ksc0, kmn0, ksc1, kmn1);
                }
            }
            {   // V dequant: word-pair rows (t=2vtp, 2vtp+1), d = 8*vwd + i
                unsigned c0 = (unsigned)vc0, c1 = (unsigned)vc1;
                #pragma unroll
                for (int i = 0; i < 8; ++i) {
                    int d = 8 * vwd + i;
                    int key = (i ^ (vwd & 7)) << 4;
                    *(unsigned*)(VtB + (((d << 7) + 4 * vtp) ^ key)) =
                        dq2(c0, c1, i, vsc0, vmn0, vsc1, vmn1);
                }
            }
        } else {
            int rt = u - 64;
            {   // K residual: thread (t=tid&63, dh=tid>>6), d-chunk dh*16
                int t = tid & 63, dh = tid >> 6;
                const float* kr = kf + (size_t)(rt * 64 + t) * Dn + dh * 16;
                int key = ((t & 7) ^ ((t >> 3) & 7)) << 4;
                #pragma unroll
                for (int s = 0; s < 2; ++s) {
                    float4 f0 = *(const float4*)(kr + s * 8);
                    float4 f1 = *(const float4*)(kr + s * 8 + 4);
                    *(short8*)(KpB + (((t << 8) + dh * 32 + s * 16) ^ key)) = pack8(f0, f1);
                }
            }
            {   // V residual: thread (d=tid&127, t4=tid>>7), t-chunk t4*16
                int d = tid & 127, t4 = tid >> 7;
                const float* vr = vf + (size_t)(rt * 64 + t4 * 16) * Dn + d;
                int key = ((d & 7) ^ ((d >> 3) & 7)) << 4;
                #pragma unroll
                for (int s = 0; s < 2; ++s) {
                    float4 f0, f1;
                    f0.x = vr[(size_t)(s * 8 + 0) * Dn]; f0.y = vr[(size_t)(s * 8 + 1) * Dn];
                    f0.z = vr[(size_t)(s * 8 + 2) * Dn]; f0.w = vr[(size_t)(s * 8 + 3) * Dn];
                    f1.x = vr[(size_t)(s * 8 + 4) * Dn]; f1.y = vr[(size_t)(s * 8 + 5) * Dn];
                    f1.z = vr[(size_t)(s * 8 + 6) * Dn]; f1.w = vr[(size_t)(s * 8 + 7) * Dn];
                    *(short8*)(VtB + (((d << 7) + t4 * 32 + s * 16) ^ key)) = pack8(f0, f1);
                }
            }
        }
        __syncthreads();   // B2: tile staged

        // ---- issue next unit's code/scale loads (drained at B3 under QK+softmax) ----
        if (u + 1 < uhi && u + 1 < 64) pf();

        // ---- S^T = K Q^T via swapped MFMA: wave handles t-half th, 16 q of group qg ----
        f32x4 s0 = {0.f,0.f,0.f,0.f}, s1 = {0.f,0.f,0.f,0.f};
        {
            int t0 = 32 * th + r, t1 = t0 + 16;
            int k0 = ((t0 & 7) ^ ((t0 >> 3) & 7)) << 4;
            int k1 = ((t1 & 7) ^ ((t1 >> 3) & 7)) << 4;
            int b0 = (t0 << 8) + (g << 4);
            int b1 = (t1 << 8) + (g << 4);
            #pragma unroll
            for (int m = 0; m < 4; ++m) {
                short8 f0 = *(const short8*)(KpB + ((b0 + (m << 6)) ^ k0));
                short8 f1 = *(const short8*)(KpB + ((b1 + (m << 6)) ^ k1));
                s0 = __builtin_amdgcn_mfma_f32_16x16x32_bf16(f0, qb[m], s0, 0, 0, 0);
                s1 = __builtin_amdgcn_mfma_f32_16x16x32_bf16(f1, qb[m], s1, 0, 0, 0);
            }
        }

        // ---- causal mask (residual tiles only): lane's t = 32th + 16mtl + 4g + reg ----
        if (u >= 64) {
            int rbase = (u - 64) * 64 + 32 * th + 4 * g;
            #pragma unroll
            for (int reg = 0; reg < 4; ++reg) {
                if (rbase + reg      > 64 + q) s0[reg] = -1e30f;
                if (rbase + 16 + reg > 64 + q) s1[reg] = -1e30f;
            }
        }

        // ---- in-register online softmax over this half's 32 t ----
        {
            float mx = fmaxf(fmaxf(fmaxf(s0[0], s0[1]), fmaxf(s0[2], s0[3])),
                             fmaxf(fmaxf(s1[0], s1[1]), fmaxf(s1[2], s1[3])));
            mx = fmaxf(mx, __shfl_xor(mx, 16));
            mx = fmaxf(mx, __shfl_xor(mx, 32));
            float mnew = fmaxf(m_run, mx);
            float p0[4], p1[4];
            #pragma unroll
            for (int reg = 0; reg < 4; ++reg) {
                p0[reg] = __expf(s0[reg] - mnew);
                p1[reg] = __expf(s1[reg] - mnew);
            }
            float sum = ((p0[0] + p0[1]) + (p0[2] + p0[3]))
                      + ((p1[0] + p1[1]) + (p1[2] + p1[3]));
            sum += __shfl_xor(sum, 16);
            sum += __shfl_xor(sum, 32);
            float alpha = __expf(m_run - mnew);
            l_run = l_run * alpha + sum;
            m_run = mnew;
            if (g == 0) al_s[w][r] = alpha;
            // P -> LDS bf16 (pairs of consecutive t)
            int pb0 = (q << 7) + 64 * th + 8 * g;
            *(unsigned*)(PlB + ((pb0     ) ^ pkey)) = pk2(p0[0], p0[1]);
            *(unsigned*)(PlB + ((pb0 +  4) ^ pkey)) = pk2(p0[2], p0[3]);
            *(unsigned*)(PlB + ((pb0 + 32) ^ pkey)) = pk2(p1[0], p1[1]);
            *(unsigned*)(PlB + ((pb0 + 36) ^ pkey)) = pk2(p1[2], p1[3]);
        }
        __syncthreads();   // B3: P + alpha visible

        // ---- O = O*alpha + P V (this half's K=32 t-slice) ----
        {
            float av[4];
            #pragma unroll
            for (int reg = 0; reg < 4; ++reg) av[reg] = al_s[w][4 * g + reg];
            #pragma unroll
            for (int nd = 0; nd < 8; ++nd) {
                #pragma unroll
                for (int reg = 0; reg < 4; ++reg) o[nd][reg] *= av[reg];
            }
            short8 pa = *(const short8*)(PlB + (((q << 7) + 64 * th + 16 * g) ^ pkey));
            #pragma unroll
            for (int nd = 0; nd < 8; ++nd) {
                int d = r + 16 * nd;
                int vkey = ((d & 7) ^ ((d >> 3) & 7)) << 4;
                short8 vb = *(const short8*)(VtB + (((d << 7) + 64 * th + 16 * g) ^ vkey));
                o[nd] = __builtin_amdgcn_mfma_f32_16x16x32_bf16(pa, vb, o[nd], 0, 0, 0);
            }
        }
    }

    // ---- merge the two t-halves in LDS, then write partial (or final) O ----
    __syncthreads();
    if (th == 1) {
        float* Osc = (float*)SMEM;
        #pragma unroll
        for (int reg = 0; reg < 4; ++reg) {
            int qrow = 16 * qg + 4 * g + reg;
            #pragma unroll
            for (int nd = 0; nd < 8; ++nd)
                Osc[qrow * 128 + r + 16 * nd] = o[nd][reg];
        }
        if (g == 0) { mlB[0][16 * qg + r] = m_run; mlB[1][16 * qg + r] = l_run; }
    } else {
        if (g == 0) { mlA[0][16 * qg + r] = m_run; mlA[1][16 * qg + r] = l_run; }
    }
    __syncthreads();
    if (th == 0) {
        const float* Osc = (const float*)SMEM;
        float* wsO = ws;
        float* wsM = ws + (size_t)128 * NS * 8192;
        float* wsL = wsM + (size_t)128 * NS * 64;
        #pragma unroll
        for (int reg = 0; reg < 4; ++reg) {
            int qrow = 16 * qg + 4 * g + reg;
            float m1v = mlA[0][qrow], l1v = mlA[1][qrow];
            float m2v = mlB[0][qrow], l2v = mlB[1][qrow];
            float M  = fmaxf(m1v, m2v);
            float w1 = __expf(m1v - M), w2 = __expf(m2v - M);
            float lt = l1v * w1 + l2v * w2;
            if (NS == 1) {
                float inv = 1.0f / lt;
                #pragma unroll
                for (int nd = 0; nd < 8; ++nd)
                    out[(size_t)bh * 8192 + qrow * 128 + r + 16 * nd] =
                        (o[nd][reg] * w1 + Osc[qrow * 128 + r + 16 * nd] * w2) * inv;
            } else {
                float* Op = wsO + (size_t)pb * 8192;
                #pragma unroll
                for (int nd = 0; nd < 8; ++nd)
                    Op[qrow * 128 + r + 16 * nd] =
                        o[nd][reg] * w1 + Osc[qrow * 128 + r + 16 * nd] * w2;
                if (r == 0) { wsM[pb * 64 + qrow] = M; wsL[pb * 64 + qrow] = lt; }
            }
        }
    }
}

template<int NS>
__global__ __launch_bounds__(256, 1)
void kivi_combine(const float* __restrict__ ws, float* __restrict__ out)
{
    const int bh  = blockIdx.x;
    const int tid = threadIdx.x;
    const int q   = tid >> 2;
    const int dq  = (tid & 3) << 5;
    const float* wsO = ws;
    const float* wsM = ws + (size_t)128 * NS * 8192;
    const float* wsL = wsM + (size_t)128 * NS * 64;

    float mv[NS];
    float M = -INFINITY;
    #pragma unroll
    for (int sp = 0; sp < NS; ++sp) {
        mv[sp] = wsM[(bh * NS + sp) * 64 + q];
        M = fmaxf(M, mv[sp]);
    }
    float lt = 0.f;
    #pragma unroll
    for (int sp = 0; sp < NS; ++sp) {
        mv[sp] = __expf(mv[sp] - M);
        lt += wsL[(bh * NS + sp) * 64 + q] * mv[sp];
    }
    float inv = 1.0f / lt;
    float4 acc[8];
    #pragma unroll
    for (int i = 0; i < 8; ++i) acc[i] = make_float4(0.f, 0.f, 0.f, 0.f);
    #pragma unroll
    for (int sp = 0; sp < NS; ++sp) {
        const float* Op = wsO + ((size_t)(bh * NS + sp)) * 8192 + q * 128 + dq;
        float wgt = mv[sp];
        #pragma unroll
        for (int i = 0; i < 8; ++i) {
            float4 f = *(const float4*)(Op + 4 * i);
            acc[i].x += f.x * wgt; acc[i].y += f.y * wgt;
            acc[i].z += f.z * wgt; acc[i].w += f.w * wgt;
        }
    }
    float* op = out + (size_t)bh * 8192 + q * 128 + dq;
    #pragma unroll
    for (int i = 0; i < 8; ++i) {
        float4 f = make_float4(acc[i].x * inv, acc[i].y * inv, acc[i].z * inv, acc[i].w * inv);
        *(float4*)(op + 4 * i) = f;
    }
}

extern "C" void kernel_launch(void* const* d_in, const int* in_sizes, int n_in,
                              void* d_out, int out_size, void* d_ws, size_t ws_size,
                              hipStream_t stream) {
    const float* qry    = (const float*)d_in[0];
    const int*   kcode  = (const int*)  d_in[1];
    const float* kscale = (const float*)d_in[2];
    const float* kmn    = (const float*)d_in[3];
    const float* kfull  = (const float*)d_in[4];
    const int*   vcode  = (const int*)  d_in[5];
    const float* vscale = (const float*)d_in[6];
    const float* vmn    = (const float*)d_in[7];
    const float* vfull  = (const float*)d_in[8];
    float* out = (float*)d_out;
    float* ws  = (float*)d_ws;

    // ws need per NS: O = 128*NS*8192 f32, m/l = 2*128*NS*64 f32
    const size_t needPerNS = ((size_t)128 * 8192 + 2 * 128 * 64) * sizeof(float);
    if (ws_size >= 4 * needPerNS) {
        kivi_attn<4><<<dim3(Bn * Hn * 4), dim3(NTHREADS), 0, stream>>>(
            qry, kcode, kscale, kmn, kfull, vcode, vscale, vmn, vfull, out, ws);
        kivi_combine<4><<<dim3(Bn * Hn), dim3(256), 0, stream>>>(ws, out);
    } else if (ws_size >= 2 * needPerNS) {
        kivi_attn<2><<<dim3(Bn * Hn * 2), dim3(NTHREADS), 0, stream>>>(
            qry, kcode, kscale, kmn, kfull, vcode, vscale, vmn, vfull, out, ws);
        kivi_combine<2><<<dim3(Bn * Hn), dim3(256), 0, stream>>>(ws, out);
    } else {
        kivi_attn<1><<<dim3(Bn * Hn), dim3(NTHREADS), 0, stream>>>(
            qry, kcode, kscale, kmn, kfull, vcode, vscale, vmn, vfull, out, ws);
    }
}